// Round 1
// baseline (3000.439 us; speedup 1.0000x reference)
//
#include <hip/hip_runtime.h>
#include <hip/hip_bf16.h>

#define NROWS 32768
#define DIM 1024
#define NCLS 10

static constexpr size_t DD = (size_t)DIM * DIM;

// ---------------- small setup kernels ----------------

__global__ void init_small_kernel(int* counts, int* cursor, float* logdets) {
    int t = threadIdx.x;
    if (t < NCLS) { counts[t] = 0; cursor[t] = 0; }
    if (t < 32) logdets[t] = 0.f;
}

__global__ void hist_kernel(const int* __restrict__ lab, int* __restrict__ counts) {
    __shared__ int h[NCLS];
    if (threadIdx.x < NCLS) h[threadIdx.x] = 0;
    __syncthreads();
    int stride = gridDim.x * blockDim.x;
    for (int i = blockIdx.x * blockDim.x + threadIdx.x; i < NROWS; i += stride)
        atomicAdd(&h[lab[i]], 1);
    __syncthreads();
    if (threadIdx.x < NCLS) atomicAdd(&counts[threadIdx.x], h[threadIdx.x]);
}

__global__ void offs_kernel(const int* __restrict__ counts, int* __restrict__ offs) {
    if (threadIdx.x == 0 && blockIdx.x == 0) {
        int s = 0;
        for (int j = 0; j < NCLS; ++j) { offs[j] = s; s += counts[j]; }
    }
}

__global__ void scatter_kernel(const int* __restrict__ lab, const int* __restrict__ offs,
                               int* __restrict__ cursor, int* __restrict__ order) {
    int stride = gridDim.x * blockDim.x;
    for (int i = blockIdx.x * blockDim.x + threadIdx.x; i < NROWS; i += stride) {
        int j = lab[i];
        int p = atomicAdd(&cursor[j], 1);
        order[offs[j] + p] = i;
    }
}

// ---------------- per-class Gram kernel ----------------
// Round-1 rewrite: 128x128 tile per block (was 64x64), 8x8 per thread as four
// 64x64 quadrants. Halves LDS bytes/FLOP (1.0 -> 0.5 B/FLOP): old kernel ran
// at 69 TF == the 69 TB/s LDS ceiling. Quadrant scheme keeps every ds_read at
// the proven conflict-free 16B-stride pattern (measured 0 conflicts).
// grid: (36 lower 128-tiles, 20 matrices). 16-row K chunks staged in LDS.

__global__ __launch_bounds__(256) void gram_kernel(
        const float* __restrict__ Z, const float* __restrict__ Zb,
        const int* __restrict__ order, const int* __restrict__ counts,
        const int* __restrict__ offs, float* __restrict__ chol) {
    const int m = blockIdx.y;            // 0..19
    const int x = blockIdx.x;            // 0..35 (lower-triangular 128-tile id)
    int ti = 0;
    while ((ti + 1) * (ti + 2) / 2 <= x) ++ti;
    const int tj = x - ti * (ti + 1) / 2;
    const int cls = m % NCLS;
    const float* __restrict__ src = (m < NCLS) ? Z : Zb;
    float* __restrict__ G = chol + (size_t)(2 + m) * DD;
    const int cnt = counts[cls];
    const int base = offs[cls];

    __shared__ float As[16][132];   // +4 pad: k-row stride 132 words (4-bank skew)
    __shared__ float Bs[16][132];

    const int t = threadIdx.x;
    const int lrow = t >> 4;        // staging k-row 0..15
    const int lf4 = t & 15;         // staging float4 slot
    const int r0 = (t >> 4) * 4;    // quadrant-local row offset 0..60
    const int c0 = (t & 15) * 4;    // quadrant-local col offset 0..60

    float acc[8][8] = {};           // [0..3]=rows r0+i, [4..7]=rows 64+r0+i

    const int nch = (cnt + 15) >> 4;
    for (int ch = 0; ch < nch; ++ch) {
        int rr = ch * 16 + lrow;
        float4 a0v = make_float4(0.f, 0.f, 0.f, 0.f);
        float4 a1v = make_float4(0.f, 0.f, 0.f, 0.f);
        float4 b0v = make_float4(0.f, 0.f, 0.f, 0.f);
        float4 b1v = make_float4(0.f, 0.f, 0.f, 0.f);
        if (rr < cnt) {
            int ridx = order[base + rr];
            const float* rowp = src + (size_t)ridx * DIM;
            a0v = *(const float4*)(rowp + ti * 128 + lf4 * 4);
            a1v = *(const float4*)(rowp + ti * 128 + 64 + lf4 * 4);
            b0v = *(const float4*)(rowp + tj * 128 + lf4 * 4);
            b1v = *(const float4*)(rowp + tj * 128 + 64 + lf4 * 4);
        }
        __syncthreads();
        *(float4*)&As[lrow][lf4 * 4] = a0v;
        *(float4*)&As[lrow][64 + lf4 * 4] = a1v;
        *(float4*)&Bs[lrow][lf4 * 4] = b0v;
        *(float4*)&Bs[lrow][64 + lf4 * 4] = b1v;
        __syncthreads();
#pragma unroll
        for (int k = 0; k < 16; ++k) {
            float4 a0 = *(const float4*)&As[k][r0];
            float4 a1 = *(const float4*)&As[k][64 + r0];
            float4 b0 = *(const float4*)&Bs[k][c0];
            float4 b1 = *(const float4*)&Bs[k][64 + c0];
            float a_[8] = {a0.x, a0.y, a0.z, a0.w, a1.x, a1.y, a1.z, a1.w};
            float b_[8] = {b0.x, b0.y, b0.z, b0.w, b1.x, b1.y, b1.z, b1.w};
#pragma unroll
            for (int i = 0; i < 8; ++i)
#pragma unroll
                for (int j = 0; j < 8; ++j)
                    acc[i][j] = fmaf(a_[i], b_[j], acc[i][j]);
        }
    }

    // direct writes: full 128x128 tile (diagonal tiles ti==tj include their
    // upper quadrants -- values are valid, matrix stays fully symmetric)
#pragma unroll
    for (int ih = 0; ih < 2; ++ih)
#pragma unroll
        for (int i = 0; i < 4; ++i) {
            int gr = ti * 128 + ih * 64 + r0 + i;
#pragma unroll
            for (int jh = 0; jh < 2; ++jh) {
                float4 v = make_float4(acc[ih * 4 + i][jh * 4 + 0],
                                       acc[ih * 4 + i][jh * 4 + 1],
                                       acc[ih * 4 + i][jh * 4 + 2],
                                       acc[ih * 4 + i][jh * 4 + 3]);
                *(float4*)&G[(size_t)gr * DIM + tj * 128 + jh * 64 + c0] = v;
            }
        }
    if (ti != tj) {
#pragma unroll
        for (int ih = 0; ih < 2; ++ih)
#pragma unroll
            for (int i = 0; i < 4; ++i)
#pragma unroll
                for (int jh = 0; jh < 2; ++jh)
#pragma unroll
                    for (int j = 0; j < 4; ++j)
                        G[(size_t)(tj * 128 + jh * 64 + c0 + j) * DIM
                          + ti * 128 + ih * 64 + r0 + i] = acc[ih * 4 + i][jh * 4 + j];
    }
}

// ---------------- build M = I + c*G matrices (fused, single pass) ----------
// Reads raw grams from slots 2..21, writes slots 0,1,22..31 and transforms
// slots 2..21 in place. Element-wise -> no cross-thread hazard.

__global__ __launch_bounds__(256) void build_kernel(float* __restrict__ chol,
                                                    const int* __restrict__ counts) {
    size_t e = (size_t)blockIdx.x * 256 + threadIdx.x;
    int a = (int)(e >> 10), b = (int)(e & 1023);
    float diag = (a == b) ? 1.f : 0.f;
    float gz[NCLS], gzb[NCLS];
    float sz = 0.f, szb = 0.f;
#pragma unroll
    for (int j = 0; j < NCLS; ++j) { gz[j] = chol[(size_t)(2 + j) * DD + e];  sz += gz[j]; }
#pragma unroll
    for (int j = 0; j < NCLS; ++j) { gzb[j] = chol[(size_t)(12 + j) * DD + e]; szb += gzb[j]; }
    chol[e]      = diag + (1.f / 16.f) * sz;    // d/(n*eps) = 1/16
    chol[DD + e] = diag + (1.f / 16.f) * szb;
#pragma unroll
    for (int j = 0; j < NCLS; ++j) {
        float c = (float)counts[j];
        float scal = 2048.f / (c + 1e-8f);       // d/(trPi*eps)
        chol[(size_t)(2 + j) * DD + e]  = diag + scal * gz[j];
        chol[(size_t)(12 + j) * DD + e] = diag + scal * gzb[j];
        chol[(size_t)(22 + j) * DD + e] = diag + (1024.f / c) * (gz[j] + gzb[j]); // d/(n2*eps)
    }
}

// ---------------- batched Cholesky: diag / trsm / syrk per NB=64 step ------

__global__ __launch_bounds__(256) void diag_kernel(float* __restrict__ chol,
                                                   float* __restrict__ logdets,
                                                   int k0) {
    const int m = blockIdx.x;
    float* __restrict__ A = chol + (size_t)m * DD;
    __shared__ float Ld[64][68];
    __shared__ float red[64];
    const int t = threadIdx.x;

    for (int e = t; e < 1024; e += 256) {
        int r = e >> 4, q = e & 15;
        *(float4*)&Ld[r][q * 4] = *(const float4*)(A + (size_t)(k0 + r) * DIM + k0 + q * 4);
    }
    __syncthreads();

    for (int kk = 0; kk < 64; ++kk) {
        if (t == 0) Ld[kk][kk] = sqrtf(Ld[kk][kk]);
        __syncthreads();
        if (t > kk && t < 64) Ld[t][kk] /= Ld[kk][kk];
        __syncthreads();
        for (int e = ((kk + 1) << 6) + t; e < 4096; e += 256) {
            int r = e >> 6, c = e & 63;
            if (c > kk && c <= r) Ld[r][c] -= Ld[r][kk] * Ld[c][kk];
        }
        __syncthreads();
    }

    if (t < 64) red[t] = logf(Ld[t][t]);
    __syncthreads();
    if (t == 0) {
        float s = 0.f;
        for (int i = 0; i < 64; ++i) s += red[i];
        atomicAdd(&logdets[m], 2.f * s);
    }

    // write factored block back (upper junk harmless, never consumed)
    for (int e = t; e < 1024; e += 256) {
        int r = e >> 4, q = e & 15;
        *(float4*)(A + (size_t)(k0 + r) * DIM + k0 + q * 4) = *(const float4*)&Ld[r][q * 4];
    }
}

// One row per thread; 64-step recurrence FULLY UNROLLED so xr[] stays in
// VGPRs (dynamic indexing would spill to scratch -- the round-2 disaster).
// L rows are wave-uniform LDS broadcasts, read as float4.
__global__ __launch_bounds__(256) void trsm_kernel(float* __restrict__ chol, int k0) {
    const int m = blockIdx.y;
    float* __restrict__ A = chol + (size_t)m * DD;
    __shared__ float Ld[64][68];
    __shared__ float rd[64];
    const int t = threadIdx.x;

    for (int e = t; e < 1024; e += 256) {
        int r = e >> 4, q = e & 15;
        *(float4*)&Ld[r][q * 4] = *(const float4*)(A + (size_t)(k0 + r) * DIM + k0 + q * 4);
    }
    __syncthreads();
    if (t < 64) rd[t] = 1.f / Ld[t][t];
    __syncthreads();

    const int r = k0 + 64 + blockIdx.x * 256 + t;
    if (r >= DIM) return;

    float xr[64];
    float4* xv = (float4*)xr;
    const float4* sp = (const float4*)(A + (size_t)r * DIM + k0);
#pragma unroll
    for (int u = 0; u < 16; ++u) xv[u] = sp[u];

#pragma unroll
    for (int kk = 0; kk < 64; ++kk) {
        float s0 = 0.f, s1 = 0.f;
        const float* lrow = &Ld[kk][0];
#pragma unroll
        for (int u = 0; u + 7 < kk; u += 8) {
            float4 l0 = *(const float4*)(lrow + u);
            float4 l1 = *(const float4*)(lrow + u + 4);
            s0 += xr[u] * l0.x + xr[u + 1] * l0.y + xr[u + 2] * l0.z + xr[u + 3] * l0.w;
            s1 += xr[u + 4] * l1.x + xr[u + 5] * l1.y + xr[u + 6] * l1.z + xr[u + 7] * l1.w;
        }
#pragma unroll
        for (int u = kk & ~7; u < kk; ++u) s0 += xr[u] * lrow[u];
        xr[kk] = (xr[kk] - (s0 + s1)) * rd[kk];
    }

    float4* dp = (float4*)(A + (size_t)r * DIM + k0);
#pragma unroll
    for (int u = 0; u < 16; ++u) dp[u] = xv[u];
}

__global__ __launch_bounds__(256) void syrk_kernel(float* __restrict__ chol, int k0) {
    const int m = blockIdx.y;
    float* __restrict__ A = chol + (size_t)m * DD;
    const int st = k0 + 64;
    int x = blockIdx.x;
    int bi = 0;
    while ((bi + 1) * (bi + 2) / 2 <= x) ++bi;
    const int bj = x - bi * (bi + 1) / 2;
    const int ra = st + bi * 64, ca = st + bj * 64;

    __shared__ float PiT[64][68];   // [k][r]
    __shared__ float PjT[64][68];
    const int t = threadIdx.x;

    for (int idx = t; idx < 1024; idx += 256) {
        int r = idx >> 4, f4 = idx & 15;
        float4 v = *(const float4*)(A + (size_t)(ra + r) * DIM + k0 + f4 * 4);
        PiT[f4 * 4 + 0][r] = v.x; PiT[f4 * 4 + 1][r] = v.y;
        PiT[f4 * 4 + 2][r] = v.z; PiT[f4 * 4 + 3][r] = v.w;
    }
    if (bj < bi) {
        for (int idx = t; idx < 1024; idx += 256) {
            int r = idx >> 4, f4 = idx & 15;
            float4 v = *(const float4*)(A + (size_t)(ca + r) * DIM + k0 + f4 * 4);
            PjT[f4 * 4 + 0][r] = v.x; PjT[f4 * 4 + 1][r] = v.y;
            PjT[f4 * 4 + 2][r] = v.z; PjT[f4 * 4 + 3][r] = v.w;
        }
    }
    __syncthreads();

    float (*Pj)[68] = (bj == bi) ? PiT : PjT;
    const int r0 = (t >> 4) * 4;
    const int c0 = (t & 15) * 4;
    float acc[4][4] = {};
#pragma unroll
    for (int u = 0; u < 64; ++u) {
        float4 a4 = *(const float4*)&PiT[u][r0];
        float4 b4 = *(const float4*)&Pj[u][c0];
        float a_[4] = {a4.x, a4.y, a4.z, a4.w};
        float b_[4] = {b4.x, b4.y, b4.z, b4.w};
#pragma unroll
        for (int i = 0; i < 4; ++i)
#pragma unroll
            for (int j = 0; j < 4; ++j)
                acc[i][j] = fmaf(a_[i], b_[j], acc[i][j]);
    }

    // subtract full tile; on diagonal tiles the upper part becomes junk that
    // is provably never read (factor/solve/syrk all touch lower+panel only)
#pragma unroll
    for (int i = 0; i < 4; ++i) {
        float* p = A + (size_t)(ra + r0 + i) * DIM + ca + c0;
        float4 v = *(const float4*)p;
        v.x -= acc[i][0]; v.y -= acc[i][1]; v.z -= acc[i][2]; v.w -= acc[i][3];
        *(float4*)p = v;
    }
}

// ---------------- final scalar combine ----------------

__global__ void finalize_kernel(const float* __restrict__ logdets,
                                const int* __restrict__ counts,
                                unsigned int* __restrict__ out) {
    if (threadIdx.x == 0 && blockIdx.x == 0) {
        const float nf = 32768.f;
        float compZ = 0.f, compH = 0.f, pc = 0.f;
        for (int j = 0; j < NCLS; ++j) {
            float c = (float)counts[j];
            float trPi = c + 1e-8f;
            compZ += trPi / (2.f * nf) * logdets[2 + j];
            compH += trPi / (2.f * nf) * logdets[12 + j];
            pc += -(logdets[22 + j] * 0.5f
                    - trPi / (4.f * c) * (logdets[2 + j] + logdets[12 + j]));
        }
        float loss_z = -(logdets[0] * 0.5f - compZ);
        float loss_h = -(logdets[1] * 0.5f - compH);
        float v = loss_z + loss_h + pc;
        unsigned int x = __float_as_uint(v);
        unsigned int r = (x + 0x7fffu + ((x >> 16) & 1u)) >> 16;  // rne bf16
        out[0] = (r << 16) | r;
    }
}

// ---------------- launch ----------------

extern "C" void kernel_launch(void* const* d_in, const int* in_sizes, int n_in,
                              void* d_out, int out_size, void* d_ws, size_t ws_size,
                              hipStream_t stream) {
    const float* Z  = (const float*)d_in[0];
    const float* Zb = (const float*)d_in[1];
    const int* lab  = (const int*)d_in[2];

    float* chol = (float*)d_ws;                       // 32 matrices, 4 MiB each
    const size_t CHOL_FLOATS = 32ull * 1024 * 1024;
    int* order   = (int*)(chol + CHOL_FLOATS);        // 32768
    int* counts  = order + NROWS;
    int* cursor  = counts + 16;
    int* offs    = cursor + 16;
    float* logdets = (float*)(offs + 16);             // 32

    init_small_kernel<<<1, 64, 0, stream>>>(counts, cursor, logdets);
    hist_kernel<<<128, 256, 0, stream>>>(lab, counts);
    offs_kernel<<<1, 64, 0, stream>>>(counts, offs);
    scatter_kernel<<<128, 256, 0, stream>>>(lab, offs, cursor, order);

    // 36 lower-triangular 128x128 tiles (nt=8), 20 matrices
    gram_kernel<<<dim3(36, 20), 256, 0, stream>>>(Z, Zb, order, counts, offs, chol);

    build_kernel<<<4096, 256, 0, stream>>>(chol, counts);

    for (int s = 0; s < 16; ++s) {
        const int k0 = s * 64;
        diag_kernel<<<32, 256, 0, stream>>>(chol, logdets, k0);
        const int nr = DIM - k0 - 64;
        if (nr > 0) {
            const int bpm = (nr + 255) / 256;
            trsm_kernel<<<dim3(bpm, 32), 256, 0, stream>>>(chol, k0);
            const int nt = nr / 64;
            const int tiles = nt * (nt + 1) / 2;
            syrk_kernel<<<dim3(tiles, 32), 256, 0, stream>>>(chol, k0);
        }
    }

    finalize_kernel<<<1, 64, 0, stream>>>(logdets, counts, (unsigned int*)d_out);
}